// Round 1
// baseline (407.203 us; speedup 1.0000x reference)
//
#include <hip/hip_runtime.h>
#include <hip/hip_cooperative_groups.h>

namespace cg = cooperative_groups;

namespace {
constexpr int kB = 64, kH = 512, kW = 512;
constexpr float kEps = 1e-6f;
constexpr int kMaxIt = 1000;
constexpr int kBlk = 256, kThr = 1024;
constexpr int kWpb = kThr / 64;          // 16 waves / block
constexpr int kTotW = kBlk * kWpb;       // 4096 waves
constexpr int kRpw = (kB * kH) / kTotW;  // 8 rows per wave
}

// persistent state (re-initialized every launch; ~1 MB)
__device__ float g_rn[kB * kH];
__device__ float g_cn[kB * kW];
__device__ float g_u [kB * kH];
__device__ float g_v [2][kB * kW];       // double-buffered column scaling
__device__ float g_kt[kB * kW];          // K^T u of the latest col phase
__device__ unsigned g_gmax[2];           // double-buffered max|beta-c| (float bits)

struct WaveMap { int b; int row0; int lane; int lw; };

__device__ __forceinline__ WaveMap wave_map() {
  int tid = threadIdx.x;
  int bid = blockIdx.x;
  int x = bid & 7;                 // heuristic XCD id
  int lb = bid >> 3;               // 0..31 within XCD
  int lw = lb * kWpb + (tid >> 6); // 0..511 within XCD
  WaveMap m;
  m.b    = x * 8 + (lw >> 6);      // 8 batches per XCD
  m.row0 = (lw & 63) * kRpw;       // 64 waves per batch, 8 rows each
  m.lane = tid & 63;
  m.lw   = lw;
  return m;
}

__device__ __forceinline__ float waveSum(float v) {
  #pragma unroll
  for (int o = 32; o; o >>= 1) v += __shfl_xor(v, o);
  return v;
}
__device__ __forceinline__ float waveMax(float v) {
  #pragma unroll
  for (int o = 32; o; o >>= 1) v = fmaxf(v, __shfl_xor(v, o));
  return v;
}
__device__ __forceinline__ float waveMin(float v) {
  #pragma unroll
  for (int o = 32; o; o >>= 1) v = fminf(v, __shfl_xor(v, o));
  return v;
}

__device__ __forceinline__ float blockSum(float v, float* red) {
  v = waveSum(v);
  int w = threadIdx.x >> 6;
  if ((threadIdx.x & 63) == 0) red[w] = v;
  __syncthreads();
  if (threadIdx.x == 0) {
    float s = red[0];
    #pragma unroll
    for (int i = 1; i < kWpb; ++i) s += red[i];
    red[0] = s;
  }
  __syncthreads();
  return red[0];
}

// column update, elementwise, replicating reference op order: (v/beta)*c
__device__ __forceinline__ float4 updv(float4 vp, float4 kt, float4 cv) {
  float4 o;
  float b0;
  b0 = vp.x * kt.x; b0 = (b0 == 0.f) ? kEps : b0; o.x = vp.x / b0 * cv.x;
  b0 = vp.y * kt.y; b0 = (b0 == 0.f) ? kEps : b0; o.y = vp.y / b0 * cv.y;
  b0 = vp.z * kt.z; b0 = (b0 == 0.f) ? kEps : b0; o.z = vp.z / b0 * cv.z;
  b0 = vp.w * kt.w; b0 = (b0 == 0.f) ? kEps : b0; o.w = vp.w / b0 * cv.w;
  return o;
}

// ---- setup: normalize r,c; v0 = 1; gmax = 0; K = exp(-(M - rowmin)) ----
__device__ void setup(const float* __restrict__ M, const float* __restrict__ r,
                      const float* __restrict__ c, float* __restrict__ K,
                      float* red) {
  int tid = threadIdx.x, bid = blockIdx.x;
  int x = bid & 7, lb = bid >> 3;
  if ((lb & 3) == 0) {  // 64 blocks, one per batch, XCD-affine
    int b = x * 8 + (lb >> 2);
    float rv = (tid < kH) ? r[b * kH + tid] : 0.f;
    float rs = blockSum(rv, red);
    if (tid < kH) g_rn[b * kH + tid] = r[b * kH + tid] / rs;
    __syncthreads();
    float cv = (tid < kW) ? c[b * kW + tid] : 0.f;
    float cs = blockSum(cv, red);
    if (tid < kW) g_cn[b * kW + tid] = c[b * kW + tid] / cs;
  }
  if (bid == 0 && tid == 0) { g_gmax[0] = 0u; g_gmax[1] = 0u; }

  WaveMap m = wave_map();
  size_t vb = (size_t)m.b * kW;
  if ((m.lw & 63) == 0) {  // one wave per batch writes v0 = ones
    float4 one = make_float4(1.f, 1.f, 1.f, 1.f);
    float4* vn = (float4*)(g_v[0] + vb);
    vn[m.lane] = one; vn[64 + m.lane] = one;
  }
  const float* Mb = M + ((size_t)m.b * kH + m.row0) * kW;
  float* Kb = K + ((size_t)m.b * kH + m.row0) * kW;
  for (int rr = 0; rr < kRpw; ++rr) {
    const float4* mr = (const float4*)(Mb + rr * kW);
    float4 a = mr[m.lane], b4 = mr[64 + m.lane];
    float mn = fminf(fminf(fminf(a.x, a.y), fminf(a.z, a.w)),
                     fminf(fminf(b4.x, b4.y), fminf(b4.z, b4.w)));
    mn = waveMin(mn);
    float4 ka, kb;
    ka.x = expf(mn - a.x);  ka.y = expf(mn - a.y);
    ka.z = expf(mn - a.z);  ka.w = expf(mn - a.w);
    kb.x = expf(mn - b4.x); kb.y = expf(mn - b4.y);
    kb.z = expf(mn - b4.z); kb.w = expf(mn - b4.w);
    float4* kr = (float4*)(Kb + rr * kW);
    kr[m.lane] = ka; kr[64 + m.lane] = kb;
  }
}

// ---- row phase (with fused column-update of previous iteration for t>=2) ----
template <bool FIRST>
__device__ void phaseA(int t, const float* __restrict__ K) {
  WaveMap m = wave_map();
  size_t vb = (size_t)m.b * kW;
  float4 va, vb4;
  if (FIRST) {
    va = make_float4(1.f, 1.f, 1.f, 1.f);
    vb4 = va;
  } else {
    int pprev = t & 1, pcur = pprev ^ 1;  // v_{t-2} lives in buf[t&1]
    const float4* vp = (const float4*)(g_v[pprev] + vb);
    const float4* kt = (const float4*)(g_kt + vb);
    const float4* cv = (const float4*)(g_cn + vb);
    float4 v1 = vp[m.lane], v2 = vp[64 + m.lane];
    float4 k1 = kt[m.lane], k2 = kt[64 + m.lane];
    float4 c1 = cv[m.lane], c2 = cv[64 + m.lane];
    va  = updv(v1, k1, c1);
    vb4 = updv(v2, k2, c2);
    if ((m.lw & 63) == 0) {  // designated writer per batch stores v_{t-1}
      float4* vn = (float4*)(g_v[pcur] + vb);
      vn[m.lane] = va; vn[64 + m.lane] = vb4;
    }
    if (blockIdx.x == 0 && threadIdx.x == 0) g_gmax[t & 1] = 0u;  // reset for B(t)
  }
  const float* Kb = K + ((size_t)m.b * kH + m.row0) * kW;
  for (int rr = 0; rr < kRpw; ++rr) {
    const float4* kr = (const float4*)(Kb + rr * kW);
    float4 k1 = kr[m.lane], k2 = kr[64 + m.lane];
    float s = k1.x * va.x + k1.y * va.y + k1.z * va.z + k1.w * va.w +
              k2.x * vb4.x + k2.y * vb4.y + k2.z * vb4.z + k2.w * vb4.w;
    s = waveSum(s);
    int ri = m.b * kH + m.row0 + rr;
    float up = FIRST ? 1.f : g_u[ri];
    float al = up * s;
    al = (al == 0.f) ? kEps : al;
    float un = up / al * g_rn[ri];
    if (m.lane == 0) g_u[ri] = un;
  }
}

// ---- column phase: K^T u, beta, global max|beta - c| ----
__device__ void phaseB(int t, const float* __restrict__ K, float* su,
                       float (*part)[128], float* red) {
  int tid = threadIdx.x, bid = blockIdx.x;
  int x = bid & 7, lb = bid >> 3;
  int b = x * 8 + (lb >> 2);   // 4 blocks per batch
  int tile = lb & 3;           // 128-column tile
  if (tid < kH) su[tid] = g_u[b * kH + tid];
  __syncthreads();
  int jj = tid & 127, q = tid >> 7;  // q in 0..7 -> 64-row stripe
  const float* col = K + (size_t)b * kH * kW + tile * 128 + jj;
  int base = q * 64;
  float a0 = 0.f, a1 = 0.f, a2 = 0.f, a3 = 0.f;
  #pragma unroll 4
  for (int ii = 0; ii < 64; ii += 4) {
    int r0 = base + ii;
    a0 = fmaf(col[(size_t)(r0 + 0) * kW], su[r0 + 0], a0);
    a1 = fmaf(col[(size_t)(r0 + 1) * kW], su[r0 + 1], a1);
    a2 = fmaf(col[(size_t)(r0 + 2) * kW], su[r0 + 2], a2);
    a3 = fmaf(col[(size_t)(r0 + 3) * kW], su[r0 + 3], a3);
  }
  part[q][jj] = (a0 + a1) + (a2 + a3);
  __syncthreads();
  float d = 0.f;
  if (tid < 128) {
    float s = 0.f;
    #pragma unroll
    for (int qq = 0; qq < 8; ++qq) s += part[qq][tid];
    int gj = b * kW + tile * 128 + tid;
    g_kt[gj] = s;
    float bet = g_v[(t - 1) & 1][gj] * s;  // beta = v_{t-1} * K^T u_t
    bet = (bet == 0.f) ? kEps : bet;
    d = fabsf(bet - g_cn[gj]);
  }
  d = waveMax(d);
  if ((tid & 63) == 0) red[tid >> 6] = d;
  __syncthreads();
  if (tid == 0) {
    float mx = red[0];
    #pragma unroll
    for (int i = 1; i < kWpb; ++i) mx = fmaxf(mx, red[i]);
    atomicMax(&g_gmax[t & 1], __float_as_uint(mx));
  }
}

// ---- final: P = diag(u) K diag(v_fin), written over K (d_out) in place ----
__device__ void phaseFinal(float* __restrict__ K, int vpar, int applyUpd) {
  WaveMap m = wave_map();
  size_t vb = (size_t)m.b * kW;
  const float4* vp = (const float4*)(g_v[vpar] + vb);
  float4 va = vp[m.lane], vb4 = vp[64 + m.lane];
  if (applyUpd) {  // maxiters exhausted while not converged: apply last col update
    const float4* kt = (const float4*)(g_kt + vb);
    const float4* cv = (const float4*)(g_cn + vb);
    va  = updv(va,  kt[m.lane],      cv[m.lane]);
    vb4 = updv(vb4, kt[64 + m.lane], cv[64 + m.lane]);
  }
  float* Kb = K + ((size_t)m.b * kH + m.row0) * kW;
  for (int rr = 0; rr < kRpw; ++rr) {
    float4* kr = (float4*)(Kb + rr * kW);
    float4 k1 = kr[m.lane], k2 = kr[64 + m.lane];
    float up = g_u[m.b * kH + m.row0 + rr];
    k1.x = up * k1.x * va.x;  k1.y = up * k1.y * va.y;
    k1.z = up * k1.z * va.z;  k1.w = up * k1.w * va.w;
    k2.x = up * k2.x * vb4.x; k2.y = up * k2.y * vb4.y;
    k2.z = up * k2.z * vb4.z; k2.w = up * k2.w * vb4.w;
    kr[m.lane] = k1; kr[64 + m.lane] = k2;
  }
}

__global__ __launch_bounds__(kThr, 4)
void sinkhorn_kernel(const float* __restrict__ M, const float* __restrict__ r,
                     const float* __restrict__ c, float* __restrict__ K) {
  cg::grid_group grid = cg::this_grid();
  __shared__ float su[kH];
  __shared__ float part[8][128];
  __shared__ float red[kWpb];

  setup(M, r, c, K, red);
  grid.sync();

  phaseA<true>(1, K);
  grid.sync();
  phaseB(1, K, su, part, red);
  grid.sync();

  int vpar = 0, applyUpd = 0;
  int t = 2;
  for (;;) {
    if (t > kMaxIt) {  // exhausted: reference applies col update iff not done
      float g = __uint_as_float(*((volatile unsigned*)&g_gmax[kMaxIt & 1]));
      vpar = (kMaxIt - 1) & 1;
      applyUpd = (g > kEps) ? 1 : 0;
      break;
    }
    float g = __uint_as_float(*((volatile unsigned*)&g_gmax[(t - 1) & 1]));
    if (g <= kEps) {  // converged at iter t-1: P = u_{t-1} K v_{t-2}
      vpar = t & 1;
      applyUpd = 0;
      break;
    }
    phaseA<false>(t, K);
    grid.sync();
    phaseB(t, K, su, part, red);
    grid.sync();
    ++t;
  }
  phaseFinal(K, vpar, applyUpd);
}

extern "C" void kernel_launch(void* const* d_in, const int* in_sizes, int n_in,
                              void* d_out, int out_size, void* d_ws, size_t ws_size,
                              hipStream_t stream) {
  (void)in_sizes; (void)n_in; (void)d_ws; (void)ws_size; (void)out_size;
  const float* M = (const float*)d_in[0];
  const float* r = (const float*)d_in[1];
  const float* c = (const float*)d_in[2];
  float* K = (float*)d_out;
  void* args[] = { (void*)&M, (void*)&r, (void*)&c, (void*)&K };
  hipLaunchCooperativeKernel((const void*)sinkhorn_kernel, dim3(kBlk), dim3(kThr),
                             args, 0, stream);
}

// Round 5
// 255.813 us; speedup vs baseline: 1.5918x; 1.5918x over previous
//
#include <hip/hip_runtime.h>
#include <hip/hip_cooperative_groups.h>

namespace cg = cooperative_groups;

namespace {
constexpr int kB = 64, kH = 512, kW = 512;
constexpr float kEps = 1e-6f;
constexpr int kMaxIt = 1000;
constexpr int kBlk = 256;   // 4 blocks per batch; block owns 128 rows
constexpr int kThr = 1024;  // 16 waves; 8 rows per wave; 8 cols x 8 rows of K per thread
constexpr int kWaves = kThr / 64;
}

// ---- cross-block state (agent-scope atomic access only; depth-2 rings) ----
__device__ float    g_KTp[2][kB][4][kW];  // per-block column partial sums (1 MB)
__device__ float    g_errp[2][kB * 4];    // per-block max|beta-c|
__device__ unsigned g_leaf[8 * 16];       // two-level monotone barrier
__device__ unsigned g_root[16];

__device__ __forceinline__ float waveRedSum(float v) {
  #pragma unroll
  for (int o = 32; o; o >>= 1) v += __shfl_xor(v, o);
  return v;
}
__device__ __forceinline__ float waveRedMax(float v) {
  #pragma unroll
  for (int o = 32; o; o >>= 1) v = fmaxf(v, __shfl_xor(v, o));
  return v;
}
__device__ __forceinline__ float waveRedMin(float v) {
  #pragma unroll
  for (int o = 32; o; o >>= 1) v = fminf(v, __shfl_xor(v, o));
  return v;
}

// Fence-free global barrier #t (t=1,2,...). __syncthreads drains vmcnt, so all
// of this block's agent-scope stores are at the coherent point before thread 0
// arrives. Spin uses agent-scope relaxed loads (bypass L1/L2) — no acquire
// fence, so caches are never invalidated.
__device__ __forceinline__ void gbar(int t) {
  __syncthreads();
  if (threadIdx.x == 0) {
    unsigned gi = (blockIdx.x & 7) * 16;
    unsigned old = atomicAdd(&g_leaf[gi], 1u);
    if (old + 1u == 32u * (unsigned)t)
      atomicAdd(&g_root[0], 1u);
    while (__hip_atomic_load(&g_root[0], __ATOMIC_RELAXED,
                             __HIP_MEMORY_SCOPE_AGENT) < 8u * (unsigned)t) {
      __builtin_amdgcn_s_sleep(4);
    }
    asm volatile("" ::: "memory");
  }
  __syncthreads();
}

__global__ __launch_bounds__(kThr, 4)
void sinkhorn_kernel(const float* __restrict__ M, const float* __restrict__ r,
                     const float* __restrict__ c, float* __restrict__ P) {
  __shared__ float s_part[kWaves][kW];  // 32 KB column partials
  __shared__ float s_v[4][kW];          // v ring: v_t at slot t&3
  __shared__ float s_cn[kW];
  __shared__ float s_rn[128];
  __shared__ float s_red[kWaves];
  __shared__ float s_bc[2];

  const int tid = threadIdx.x, bid = blockIdx.x;
  const int b = bid >> 2;      // batch
  const int q = bid & 3;       // row-quarter
  const int w = tid >> 6, lane = tid & 63;
  const int row0 = q * 128 + w * 8;

  // ---- init cross-block structures; publish with the ONLY fenced sync ----
  if (bid == 0 && tid == 0) {
    #pragma unroll
    for (int i = 0; i < 8; ++i) atomicExch(&g_leaf[i * 16], 0u);
    atomicExch(&g_root[0], 0u);
  }
  if (tid == 0)
    __hip_atomic_store(&g_errp[0][bid], __builtin_inff(),
                       __ATOMIC_RELAXED, __HIP_MEMORY_SCOPE_AGENT);
  cg::this_grid().sync();

  // ---- setup: r_n, c_n, v_1 = 1; K = exp(rowmin - M) into registers ----
  {
    float rv = (tid < kH) ? r[(size_t)b * kH + tid] : 0.f;
    float ws = waveRedSum(rv);
    if (lane == 0) s_red[w] = ws;
    __syncthreads();
    if (tid == 0) {
      float s = s_red[0];
      #pragma unroll
      for (int i = 1; i < kWaves; ++i) s += s_red[i];
      s_bc[0] = s;
    }
    __syncthreads();
    float rsum = s_bc[0];
    if (tid < 128) s_rn[tid] = r[(size_t)b * kH + q * 128 + tid] / rsum;
    __syncthreads();

    float cv = (tid < kW) ? c[(size_t)b * kW + tid] : 0.f;
    ws = waveRedSum(cv);
    if (lane == 0) s_red[w] = ws;
    __syncthreads();
    if (tid == 0) {
      float s = s_red[0];
      #pragma unroll
      for (int i = 1; i < kWaves; ++i) s += s_red[i];
      s_bc[0] = s;
    }
    __syncthreads();
    float csum = s_bc[0];
    if (tid < kW) {
      s_cn[tid] = c[(size_t)b * kW + tid] / csum;
      s_v[1][tid] = 1.0f;
    }
  }

  float4 kreg[8][2];   // this thread's 8 rows x 8 cols of K (stays in VGPRs)
  #pragma unroll
  for (int rr = 0; rr < 8; ++rr) {
    const float4* Mr = (const float4*)(M + ((size_t)b * kH + row0 + rr) * kW);
    float4 a = Mr[lane], d = Mr[64 + lane];
    float mn = fminf(fminf(fminf(a.x, a.y), fminf(a.z, a.w)),
                     fminf(fminf(d.x, d.y), fminf(d.z, d.w)));
    mn = waveRedMin(mn);
    float4 ka, kb;
    ka.x = expf(mn - a.x); ka.y = expf(mn - a.y);
    ka.z = expf(mn - a.z); ka.w = expf(mn - a.w);
    kb.x = expf(mn - d.x); kb.y = expf(mn - d.y);
    kb.z = expf(mn - d.z); kb.w = expf(mn - d.w);
    kreg[rr][0] = ka; kreg[rr][1] = kb;
  }
  __syncthreads();

  // ---- iteration loop: one barrier per iteration, K in registers ----
  float u_prev[8], u_cur[8];
  #pragma unroll
  for (int i = 0; i < 8; ++i) u_prev[i] = 1.f;

  int fin_vslot = 0;
  int t = 1;
  for (;; ++t) {
    const int p = t & 3;   // v_t slot
    const int h = t & 1;   // KT/err slot
    const float4* v4 = (const float4*)s_v[p];
    float4 va = v4[lane], vb = v4[64 + lane];
    float4 cp0 = make_float4(0.f, 0.f, 0.f, 0.f);
    float4 cp1 = make_float4(0.f, 0.f, 0.f, 0.f);
    #pragma unroll
    for (int rr = 0; rr < 8; ++rr) {
      float4 k0 = kreg[rr][0], k1 = kreg[rr][1];
      float s = k0.x * va.x + k0.y * va.y + k0.z * va.z + k0.w * va.w +
                k1.x * vb.x + k1.y * vb.y + k1.z * vb.z + k1.w * vb.w;
      s = waveRedSum(s);
      float up = u_prev[rr];
      float al = up * s;
      al = (al == 0.f) ? kEps : al;
      float un = up / al * s_rn[w * 8 + rr];
      u_cur[rr] = un;
      cp0.x = fmaf(un, k0.x, cp0.x); cp0.y = fmaf(un, k0.y, cp0.y);
      cp0.z = fmaf(un, k0.z, cp0.z); cp0.w = fmaf(un, k0.w, cp0.w);
      cp1.x = fmaf(un, k1.x, cp1.x); cp1.y = fmaf(un, k1.y, cp1.y);
      cp1.z = fmaf(un, k1.z, cp1.z); cp1.w = fmaf(un, k1.w, cp1.w);
    }
    float4* pp = (float4*)&s_part[w][0];
    pp[lane] = cp0; pp[64 + lane] = cp1;
    __syncthreads();
    if (tid < kW) {
      float s = 0.f;
      #pragma unroll
      for (int ww = 0; ww < kWaves; ++ww) s += s_part[ww][tid];
      __hip_atomic_store(&g_KTp[h][b][q][tid], s,
                         __ATOMIC_RELAXED, __HIP_MEMORY_SCOPE_AGENT);
    }

    gbar(t);   // all blocks' KTp(t) complete beyond this point

    // post: beta_t, v_{t+1}, err_t (fixed-order deterministic sums)
    float err = 0.f;
    if (tid < kW) {
      float kt = 0.f;
      #pragma unroll
      for (int qq = 0; qq < 4; ++qq)
        kt += __hip_atomic_load(&g_KTp[h][b][qq][tid],
                                __ATOMIC_RELAXED, __HIP_MEMORY_SCOPE_AGENT);
      float vt = s_v[p][tid];
      float beta = vt * kt;
      beta = (beta == 0.f) ? kEps : beta;
      float cn = s_cn[tid];
      s_v[(t + 1) & 3][tid] = vt / beta * cn;
      err = fabsf(beta - cn);
    }
    err = waveRedMax(err);
    if (lane == 0) s_red[w] = err;
    __syncthreads();
    if (tid == 0) {
      float mx = s_red[0];
      #pragma unroll
      for (int i = 1; i < kWaves; ++i) mx = fmaxf(mx, s_red[i]);
      __hip_atomic_store(&g_errp[h][bid], mx,
                         __ATOMIC_RELAXED, __HIP_MEMORY_SCOPE_AGENT);
    }
    __syncthreads();   // protect s_red reuse below

    // verdict(t-1): all blocks' err_{t-1} complete since barrier(t)
    float gv = 0.f;
    if (tid < kBlk) {
      gv = __hip_atomic_load(&g_errp[(t - 1) & 1][tid],
                             __ATOMIC_RELAXED, __HIP_MEMORY_SCOPE_AGENT);
    }
    gv = waveRedMax(gv);
    if (lane == 0 && w < 4) s_red[w] = gv;
    __syncthreads();
    gv = fmaxf(fmaxf(s_red[0], s_red[1]), fmaxf(s_red[2], s_red[3]));

    if (gv <= kEps) {        // converged at T = t-1: P = u_{t-1} K v_{t-1}
      fin_vslot = (t - 1) & 3;
      break;
    }
    if (t == kMaxIt + 1) {   // 1000 bodies ran, done(1000) false: u_1000 K v_1001
      fin_vslot = t & 3;
      break;
    }
    #pragma unroll
    for (int i = 0; i < 8; ++i) u_prev[i] = u_cur[i];
  }

  // ---- final: P = diag(u_prev) K diag(v_fin), K straight from registers ----
  const float4* vf4 = (const float4*)s_v[fin_vslot];
  float4 vfa = vf4[lane], vfb = vf4[64 + lane];
  #pragma unroll
  for (int rr = 0; rr < 8; ++rr) {
    float4 k0 = kreg[rr][0], k1 = kreg[rr][1];
    float un = u_prev[rr];
    k0.x = un * k0.x * vfa.x; k0.y = un * k0.y * vfa.y;
    k0.z = un * k0.z * vfa.z; k0.w = un * k0.w * vfa.w;
    k1.x = un * k1.x * vfb.x; k1.y = un * k1.y * vfb.y;
    k1.z = un * k1.z * vfb.z; k1.w = un * k1.w * vfb.w;
    float4* Pr = (float4*)(P + ((size_t)b * kH + row0 + rr) * kW);
    Pr[lane] = k0; Pr[64 + lane] = k1;
  }
}

extern "C" void kernel_launch(void* const* d_in, const int* in_sizes, int n_in,
                              void* d_out, int out_size, void* d_ws, size_t ws_size,
                              hipStream_t stream) {
  (void)in_sizes; (void)n_in; (void)d_ws; (void)ws_size; (void)out_size;
  const float* M = (const float*)d_in[0];
  const float* r = (const float*)d_in[1];
  const float* c = (const float*)d_in[2];
  float* P = (float*)d_out;
  void* args[] = { (void*)&M, (void*)&r, (void*)&c, (void*)&P };
  hipLaunchCooperativeKernel((const void*)sinkhorn_kernel, dim3(kBlk), dim3(kThr),
                             args, 0, stream);
}